// Round 1
// baseline (115.564 us; speedup 1.0000x reference)
//
#include <hip/hip_runtime.h>
#include <math.h>

#define LENL 96
#define NCH 32
#define CCH 16
#define NEXP 4
#define NB 512
#define NFREQ 47
#define SPLIT 8
#define PI_D 3.141592653589793238462643383279502884

// ---------------- Kernel 1: gating path, one block per batch row ----------------
__global__ __launch_bounds__(128) void k1_gates(
    const float* __restrict__ x,        // (512,96,32,16)
    const float* __restrict__ W_start,  // (1,32)
    const float* __restrict__ b_start,  // (1,)
    const float* __restrict__ W_gate,   // (4,96)
    const float* __restrict__ b_gate,   // (4,)
    const float* __restrict__ W_exp,    // (4,16,16)
    const float* __restrict__ b_exp,    // (4,16)
    float* __restrict__ Mws,            // (512,256) combined expert matrix
    float* __restrict__ biasws,         // (512,16)
    float* __restrict__ gws)            // (512,4) gates
{
    const int b = blockIdx.x;
    const int t = threadIdx.x;

    __shared__ float xs[LENL][NCH + 1];    // stride 33 -> conflict-free
    __shared__ float tr[LENL][NCH + 1];
    __shared__ double twcD[LENL], twsD[LENL];
    __shared__ float twcF[LENL], twsF[LENL];
    __shared__ double Xr[NCH][NFREQ + 1], Xi[NCH][NFREQ + 1];
    __shared__ float selA[NCH][3], selB[NCH][3];
    __shared__ int selF[NCH][3];
    __shared__ float g_s[LENL];
    __shared__ float logit_s[NEXP];
    __shared__ float gsel[2];
    __shared__ int esel[2];

    // twiddle tables (fp64 for DFT selection fidelity, fp32 for reconstruction)
    for (int m = t; m < LENL; m += 128) {
        double ang = (2.0 * PI_D * (double)m) / (double)LENL;
        double c = cos(ang), s = sin(ang);
        twcD[m] = c; twsD[m] = s;
        twcF[m] = (float)c; twsF[m] = (float)s;
    }
    // load xs = x[b,:,:,0]
    for (int idx = t; idx < LENL * NCH; idx += 128) {
        int l = idx >> 5, n = idx & 31;
        xs[l][n] = x[((size_t)b * (LENL * NCH) + (size_t)idx) * CCH];
    }
    __syncthreads();

    // trend = (ma4 + ma8 + ma12) / 3, edge-replicated windows
    for (int idx = t; idx < LENL * NCH; idx += 128) {
        int l = idx >> 5, n = idx & 31;
        float s4 = 0.f;
        #pragma unroll
        for (int j = -1; j <= 2; ++j) {
            int li = l + j; li = li < 0 ? 0 : (li > 95 ? 95 : li);
            s4 += xs[li][n];
        }
        float s8 = s4;
        {
            int j, li;
            j = -3; li = l + j; li = li < 0 ? 0 : (li > 95 ? 95 : li); s8 += xs[li][n];
            j = -2; li = l + j; li = li < 0 ? 0 : (li > 95 ? 95 : li); s8 += xs[li][n];
            j =  3; li = l + j; li = li < 0 ? 0 : (li > 95 ? 95 : li); s8 += xs[li][n];
            j =  4; li = l + j; li = li < 0 ? 0 : (li > 95 ? 95 : li); s8 += xs[li][n];
        }
        float s12 = s8;
        {
            int j, li;
            j = -5; li = l + j; li = li < 0 ? 0 : (li > 95 ? 95 : li); s12 += xs[li][n];
            j = -4; li = l + j; li = li < 0 ? 0 : (li > 95 ? 95 : li); s12 += xs[li][n];
            j =  5; li = l + j; li = li < 0 ? 0 : (li > 95 ? 95 : li); s12 += xs[li][n];
            j =  6; li = l + j; li = li < 0 ? 0 : (li > 95 ? 95 : li); s12 += xs[li][n];
        }
        tr[l][n] = (s4 * 0.25f + s8 * 0.125f + s12 * (1.f / 12.f)) * (1.f / 3.f);
    }

    // DFT bins f=1..47 per n (f-major task order: 32 consecutive lanes share f)
    for (int task = t; task < NFREQ * NCH; task += 128) {
        int fi = task >> 5;
        int n = task & 31;
        int f = fi + 1;
        double ar = 0.0, ai = 0.0;
        int m = 0;
        for (int l = 0; l < LENL; ++l) {
            double v = (double)xs[l][n];
            ar += v * twcD[m];
            ai -= v * twsD[m];
            m += f; if (m >= LENL) m -= LENL;
        }
        Xr[n][fi] = ar; Xi[n][fi] = ai;
    }
    __syncthreads();

    // top-3 |X|^2 per n (strict > keeps lowest index on ties, matching lax.top_k)
    if (t < NCH) {
        int n = t;
        double m1 = -1.0, m2 = -1.0, m3 = -1.0;
        int i1 = 0, i2 = 0, i3 = 0;
        for (int fi = 0; fi < NFREQ; ++fi) {
            double vr = Xr[n][fi], vi = Xi[n][fi];
            double mag = vr * vr + vi * vi;
            if (mag > m1)      { m3 = m2; i3 = i2; m2 = m1; i2 = i1; m1 = mag; i1 = fi; }
            else if (mag > m2) { m3 = m2; i3 = i2; m2 = mag; i2 = fi; }
            else if (mag > m3) { m3 = mag; i3 = fi; }
        }
        const float sc = 2.0f / (float)LENL;
        selF[n][0] = i1 + 1; selA[n][0] = sc * (float)Xr[n][i1]; selB[n][0] = sc * (float)Xi[n][i1];
        selF[n][1] = i2 + 1; selA[n][1] = sc * (float)Xr[n][i2]; selB[n][1] = sc * (float)Xi[n][i2];
        selF[n][2] = i3 + 1; selA[n][2] = sc * (float)Xr[n][i3]; selB[n][2] = sc * (float)Xi[n][i3];
    }
    __syncthreads();

    // new_x = xs + trend + seasonal (in place)
    for (int idx = t; idx < LENL * NCH; idx += 128) {
        int l = idx >> 5, n = idx & 31;
        float w = 0.f;
        #pragma unroll
        for (int j = 0; j < 3; ++j) {
            int m = (selF[n][j] * l) % LENL;
            w += selA[n][j] * twcF[m] - selB[n][j] * twsF[m];
        }
        xs[l][n] += tr[l][n] + w;
    }
    __syncthreads();

    // g[l] = sum_n new_x[l][n] * W_start[n] + b_start
    if (t < LENL) {
        float acc = b_start[0];
        #pragma unroll
        for (int n = 0; n < NCH; ++n) acc += xs[t][n] * W_start[n];
        g_s[t] = acc;
    }
    __syncthreads();

    // logits[e] = sum_l g[l] * W_gate[e,l] + b_gate[e]
    if (t < NEXP) {
        float acc = b_gate[t];
        for (int l = 0; l < LENL; ++l) acc += g_s[l] * W_gate[t * LENL + l];
        logit_s[t] = acc;
    }
    __syncthreads();

    // top-2 + softmax
    if (t == 0) {
        int i1 = 0;
        for (int e = 1; e < NEXP; ++e) if (logit_s[e] > logit_s[i1]) i1 = e;
        int i2 = (i1 == 0) ? 1 : 0;
        for (int e = 0; e < NEXP; ++e) if (e != i1 && logit_s[e] > logit_s[i2]) i2 = e;
        float v1 = logit_s[i1], v2 = logit_s[i2];
        float e2v = expf(v2 - v1);
        float inv = 1.f / (1.f + e2v);
        float g1 = inv, g2 = e2v * inv;
        esel[0] = i1; esel[1] = i2; gsel[0] = g1; gsel[1] = g2;
        for (int e = 0; e < NEXP; ++e)
            gws[b * NEXP + e] = (e == i1) ? g1 : ((e == i2) ? g2 : 0.f);
    }
    __syncthreads();

    // combined expert matrix + bias for this row
    {
        float ga = gsel[0], gb = gsel[1];
        int ea = esel[0], eb = esel[1];
        for (int idx = t; idx < CCH * CCH; idx += 128)
            Mws[b * 256 + idx] = ga * W_exp[ea * 256 + idx] + gb * W_exp[eb * 256 + idx];
        if (t < CCH)
            biasws[b * CCH + t] = ga * b_exp[ea * CCH + t] + gb * b_exp[eb * CCH + t];
    }
}

// ---------------- Kernel 2: out = x + x @ M_b + bias_b (memory-bound) ----------------
__global__ __launch_bounds__(256) void k2_out(
    const float* __restrict__ x,
    const float* __restrict__ Mws,
    const float* __restrict__ biasws,
    float* __restrict__ out)
{
    const int blk = blockIdx.x;
    const int b = blk >> 3;            // SPLIT = 8
    const int chunk = blk & 7;
    const int t = threadIdx.x;
    const int lane = t & 63;
    const int wv = t >> 6;
    const int cg = lane & 3;                // channel group (4 outputs)
    const int prow = (wv << 4) + (lane >> 2); // 0..63 position within iteration

    // M column chunk in registers: M[f][cg*4 .. cg*4+3], f = 0..15
    const float* Mb = Mws + b * 256 + cg * 4;
    float4 m0  = *(const float4*)(Mb + 0 * 16);
    float4 m1  = *(const float4*)(Mb + 1 * 16);
    float4 m2  = *(const float4*)(Mb + 2 * 16);
    float4 m3  = *(const float4*)(Mb + 3 * 16);
    float4 m4  = *(const float4*)(Mb + 4 * 16);
    float4 m5  = *(const float4*)(Mb + 5 * 16);
    float4 m6  = *(const float4*)(Mb + 6 * 16);
    float4 m7  = *(const float4*)(Mb + 7 * 16);
    float4 m8  = *(const float4*)(Mb + 8 * 16);
    float4 m9  = *(const float4*)(Mb + 9 * 16);
    float4 m10 = *(const float4*)(Mb + 10 * 16);
    float4 m11 = *(const float4*)(Mb + 11 * 16);
    float4 m12 = *(const float4*)(Mb + 12 * 16);
    float4 m13 = *(const float4*)(Mb + 13 * 16);
    float4 m14 = *(const float4*)(Mb + 14 * 16);
    float4 m15 = *(const float4*)(Mb + 15 * 16);
    float4 bias = *(const float4*)(biasws + b * CCH + cg * 4);

    const size_t base = (size_t)b * (LENL * NCH * CCH);
    const float* xb = x + base;
    float* ob = out + base;
    const int posBase = chunk * (LENL * NCH / SPLIT); // 384 positions per chunk

    #pragma unroll
    for (int i = 0; i < (LENL * NCH / SPLIT) / 64; ++i) { // 6 iterations
        int pos = posBase + i * 64 + prow;
        const float* xr = xb + (size_t)pos * CCH;
        float4 x0 = *(const float4*)(xr + 0);
        float4 x1 = *(const float4*)(xr + 4);
        float4 x2 = *(const float4*)(xr + 8);
        float4 x3 = *(const float4*)(xr + 12);
        float4 acc = bias;
        #define STEPF(v, M) acc.x += (v) * (M).x; acc.y += (v) * (M).y; acc.z += (v) * (M).z; acc.w += (v) * (M).w;
        STEPF(x0.x, m0)  STEPF(x0.y, m1)  STEPF(x0.z, m2)  STEPF(x0.w, m3)
        STEPF(x1.x, m4)  STEPF(x1.y, m5)  STEPF(x1.z, m6)  STEPF(x1.w, m7)
        STEPF(x2.x, m8)  STEPF(x2.y, m9)  STEPF(x2.z, m10) STEPF(x2.w, m11)
        STEPF(x3.x, m12) STEPF(x3.y, m13) STEPF(x3.z, m14) STEPF(x3.w, m15)
        #undef STEPF
        float4 xo = (cg == 0) ? x0 : ((cg == 1) ? x1 : ((cg == 2) ? x2 : x3));
        acc.x += xo.x; acc.y += xo.y; acc.z += xo.z; acc.w += xo.w;
        *(float4*)(ob + (size_t)pos * CCH + cg * 4) = acc;
    }
}

// ---------------- Kernel 3: balance loss ----------------
__global__ __launch_bounds__(256) void k3_loss(
    const float* __restrict__ gws, float* __restrict__ loss_out)
{
    __shared__ float sh[8][256];
    const int t = threadIdx.x;
    float imp[4] = {0, 0, 0, 0}, ld[4] = {0, 0, 0, 0};
    for (int b = t; b < NB; b += 256) {
        #pragma unroll
        for (int e = 0; e < 4; ++e) {
            float v = gws[b * 4 + e];
            imp[e] += v;
            ld[e] += (v > 0.f) ? 1.f : 0.f;
        }
    }
    #pragma unroll
    for (int e = 0; e < 4; ++e) { sh[e][t] = imp[e]; sh[4 + e][t] = ld[e]; }
    __syncthreads();
    if (t < 8) {
        float s = 0.f;
        for (int i = 0; i < 256; ++i) s += sh[t][i];
        sh[t][0] = s;
    }
    __syncthreads();
    if (t == 0) {
        float a = sh[0][0], b2 = sh[1][0], c = sh[2][0], d = sh[3][0];
        float mean = (a + b2 + c + d) * 0.25f;
        float var = ((a - mean) * (a - mean) + (b2 - mean) * (b2 - mean) +
                     (c - mean) * (c - mean) + (d - mean) * (d - mean)) * (1.f / 3.f);
        float L1 = var / (mean * mean + 1e-10f);
        a = sh[4][0]; b2 = sh[5][0]; c = sh[6][0]; d = sh[7][0];
        mean = (a + b2 + c + d) * 0.25f;
        var = ((a - mean) * (a - mean) + (b2 - mean) * (b2 - mean) +
               (c - mean) * (c - mean) + (d - mean) * (d - mean)) * (1.f / 3.f);
        float L2 = var / (mean * mean + 1e-10f);
        *loss_out = 0.01f * (L1 + L2);
    }
}

extern "C" void kernel_launch(void* const* d_in, const int* in_sizes, int n_in,
                              void* d_out, int out_size, void* d_ws, size_t ws_size,
                              hipStream_t stream)
{
    const float* x       = (const float*)d_in[0];
    const float* W_start = (const float*)d_in[1];
    const float* b_start = (const float*)d_in[2];
    const float* W_gate  = (const float*)d_in[3];
    const float* b_gate  = (const float*)d_in[4];
    const float* W_exp   = (const float*)d_in[5];
    const float* b_exp   = (const float*)d_in[6];
    float* out = (float*)d_out;

    float* Mws    = (float*)d_ws;            // 512*256 floats
    float* biasws = Mws + NB * 256;          // 512*16
    float* gws    = biasws + NB * CCH;       // 512*4

    k1_gates<<<NB, 128, 0, stream>>>(x, W_start, b_start, W_gate, b_gate,
                                     W_exp, b_exp, Mws, biasws, gws);
    k2_out<<<NB * SPLIT, 256, 0, stream>>>(x, Mws, biasws, out);
    k3_loss<<<1, 256, 0, stream>>>(gws, out + (size_t)out_size - 1);
}

// Round 2
// 85.313 us; speedup vs baseline: 1.3546x; 1.3546x over previous
//
#include <hip/hip_runtime.h>
#include <math.h>

#define LENL 96
#define NCH 32
#define CCH 16
#define NEXP 4
#define NB 512
#define SPLIT 8
#define TWO_PI_D 6.283185307179586476925286766559

// ---------------- Kernel A: gather + fp64 DFT + top-3 selection ----------------
// grid = NB*2 blocks of 256; block (b, half) handles 16 of the 32 series of row b.
// wave w handles 4 series; lane = frequency bin (1..47 on lanes 0..46).
__global__ __launch_bounds__(256) void k_dft(
    const float* __restrict__ x,        // (512,96,32,16)
    const float* __restrict__ W_start,  // (1,32)
    float* __restrict__ xs_t,           // (512,32,96) compact series
    float2* __restrict__ selAB,         // (512*32*3) (a,b) with Ws[n]*2/96 folded
    int* __restrict__ selFq)            // (512*32*3) selected freq index (1..47)
{
    const int bi = blockIdx.x;
    const int b = bi >> 1;
    const int n0 = (bi & 1) << 4;
    const int t = threadIdx.x;
    const int w = t >> 6, lane = t & 63;

    __shared__ double2 twp[LENL];           // (cos, -sin) fp64
    __shared__ double xd[16][LENL];         // series in fp64
    __shared__ double mags[4][4][48];
    __shared__ float reX[4][4][48], imX[4][4][48];

    if (t < LENL) {
        double ang = TWO_PI_D * (double)t / 96.0;
        twp[t] = make_double2(cos(ang), -sin(ang));
    }
    for (int idx = t; idx < 16 * LENL; idx += 256) {
        int s = idx / LENL, l = idx - s * LENL;
        float v = x[(((size_t)b * LENL + l) * NCH + (n0 + s)) * CCH];
        xd[s][l] = (double)v;
        xs_t[((size_t)b * NCH + (n0 + s)) * LENL + l] = v;   // coalesced over l
    }
    __syncthreads();

    const int f = (lane < 47) ? (lane + 1) : 0;
    double ar0 = 0, ai0 = 0, ar1 = 0, ai1 = 0, ar2 = 0, ai2 = 0, ar3 = 0, ai3 = 0;
    const double* x0p = xd[w * 4 + 0];
    const double* x1p = xd[w * 4 + 1];
    const double* x2p = xd[w * 4 + 2];
    const double* x3p = xd[w * 4 + 3];
    int m = 0;
    #pragma unroll 4
    for (int l = 0; l < LENL; ++l) {
        double2 tw = twp[m];
        double v0 = x0p[l], v1 = x1p[l], v2 = x2p[l], v3 = x3p[l];
        ar0 = fma(v0, tw.x, ar0); ai0 = fma(v0, tw.y, ai0);
        ar1 = fma(v1, tw.x, ar1); ai1 = fma(v1, tw.y, ai1);
        ar2 = fma(v2, tw.x, ar2); ai2 = fma(v2, tw.y, ai2);
        ar3 = fma(v3, tw.x, ar3); ai3 = fma(v3, tw.y, ai3);
        m += f; if (m >= LENL) m -= LENL;
    }
    if (lane < 47) {
        mags[w][0][lane] = ar0 * ar0 + ai0 * ai0; reX[w][0][lane] = (float)ar0; imX[w][0][lane] = (float)ai0;
        mags[w][1][lane] = ar1 * ar1 + ai1 * ai1; reX[w][1][lane] = (float)ar1; imX[w][1][lane] = (float)ai1;
        mags[w][2][lane] = ar2 * ar2 + ai2 * ai2; reX[w][2][lane] = (float)ar2; imX[w][2][lane] = (float)ai2;
        mags[w][3][lane] = ar3 * ar3 + ai3 * ai3; reX[w][3][lane] = (float)ar3; imX[w][3][lane] = (float)ai3;
    }
    __syncthreads();

    if (lane < 4) {
        const int p = lane;
        double m1 = -1.0, m2 = -1.0, m3 = -1.0;
        int i1 = 0, i2 = 0, i3 = 0;
        for (int fi = 0; fi < 47; ++fi) {
            double mg = mags[w][p][fi];
            if (mg > m1)      { m3 = m2; i3 = i2; m2 = m1; i2 = i1; m1 = mg; i1 = fi; }
            else if (mg > m2) { m3 = m2; i3 = i2; m2 = mg; i2 = fi; }
            else if (mg > m3) { m3 = mg; i3 = fi; }
        }
        const int n = n0 + w * 4 + p;
        const float sc = W_start[n] * (2.0f / 96.0f);
        const size_t base = ((size_t)b * NCH + n) * 3;
        selFq[base + 0] = i1 + 1; selAB[base + 0] = make_float2(sc * reX[w][p][i1], sc * imX[w][p][i1]);
        selFq[base + 1] = i2 + 1; selAB[base + 1] = make_float2(sc * reX[w][p][i2], sc * imX[w][p][i2]);
        selFq[base + 2] = i3 + 1; selAB[base + 2] = make_float2(sc * reX[w][p][i3], sc * imX[w][p][i3]);
    }
}

// ---------------- Kernel B: y + trend(y) + seasonal + logits + gates + M ----------------
__global__ __launch_bounds__(128) void k_gate(
    const float* __restrict__ xs_t,
    const float2* __restrict__ selAB,
    const int* __restrict__ selFq,
    const float* __restrict__ W_start,
    const float* __restrict__ b_start,
    const float* __restrict__ W_gate,   // (4,96)
    const float* __restrict__ b_gate,   // (4,)
    const float* __restrict__ W_exp,    // (4,16,16)
    const float* __restrict__ b_exp,    // (4,16)
    float* __restrict__ Mws, float* __restrict__ biasws, float* __restrict__ gws)
{
    const int b = blockIdx.x, t = threadIdx.x;
    __shared__ float2 twf[LENL];        // (cos, -sin) fp32
    __shared__ float Wsm[NCH];
    __shared__ float As[96], Bs[96];
    __shared__ int Fs[96];
    __shared__ float yb[LENL], g_sh[LENL];
    __shared__ float logit_s[NEXP];
    __shared__ float gsel[2];
    __shared__ int esel[2];

    if (t < LENL) {
        double ang = TWO_PI_D * (double)t / 96.0;
        twf[t] = make_float2((float)cos(ang), (float)(-sin(ang)));
        float2 ab = selAB[(size_t)b * 96 + t];
        As[t] = ab.x; Bs[t] = ab.y;
        Fs[t] = selFq[(size_t)b * 96 + t];
    }
    if (t < NCH) Wsm[t] = W_start[t];
    __syncthreads();

    if (t < LENL) {
        float yv = 0.f;
        #pragma unroll
        for (int n = 0; n < NCH; ++n)
            yv += xs_t[((size_t)b * NCH + n) * LENL + t] * Wsm[n];
        yb[t] = yv;
    }
    __syncthreads();

    if (t < LENL) {
        // trend(y): ma4 + ma8 + ma12 with edge-replication
        float s4 = 0.f;
        #pragma unroll
        for (int j = -1; j <= 2; ++j) {
            int li = t + j; li = li < 0 ? 0 : (li > 95 ? 95 : li);
            s4 += yb[li];
        }
        float s8 = s4;
        {
            int li;
            li = t - 3; li = li < 0 ? 0 : li; s8 += yb[li];
            li = t - 2; li = li < 0 ? 0 : li; s8 += yb[li];
            li = t + 3; li = li > 95 ? 95 : li; s8 += yb[li];
            li = t + 4; li = li > 95 ? 95 : li; s8 += yb[li];
        }
        float s12 = s8;
        {
            int li;
            li = t - 5; li = li < 0 ? 0 : li; s12 += yb[li];
            li = t - 4; li = li < 0 ? 0 : li; s12 += yb[li];
            li = t + 5; li = li > 95 ? 95 : li; s12 += yb[li];
            li = t + 6; li = li > 95 ? 95 : li; s12 += yb[li];
        }
        float tr = (s4 * 0.25f + s8 * 0.125f + s12 * (1.f / 12.f)) * (1.f / 3.f);

        float se = 0.f;
        for (int k = 0; k < 96; ++k) {
            int m = (Fs[k] * t) % LENL;
            float2 c = twf[m];
            se += As[k] * c.x + Bs[k] * c.y;
        }
        g_sh[t] = yb[t] + tr + se + b_start[0];
    }
    __syncthreads();

    if (t < NEXP) {
        float acc = b_gate[t];
        for (int l = 0; l < LENL; ++l) acc += g_sh[l] * W_gate[t * LENL + l];
        logit_s[t] = acc;
    }
    __syncthreads();

    if (t == 0) {
        int i1 = 0;
        for (int e = 1; e < NEXP; ++e) if (logit_s[e] > logit_s[i1]) i1 = e;
        int i2 = (i1 == 0) ? 1 : 0;
        for (int e = 0; e < NEXP; ++e) if (e != i1 && logit_s[e] > logit_s[i2]) i2 = e;
        float v1 = logit_s[i1], v2 = logit_s[i2];
        float e2v = expf(v2 - v1);
        float inv = 1.f / (1.f + e2v);
        esel[0] = i1; esel[1] = i2; gsel[0] = inv; gsel[1] = e2v * inv;
        for (int e = 0; e < NEXP; ++e)
            gws[b * NEXP + e] = (e == i1) ? inv : ((e == i2) ? e2v * inv : 0.f);
    }
    __syncthreads();

    {
        float ga = gsel[0], gb = gsel[1];
        int ea = esel[0], eb = esel[1];
        for (int idx = t; idx < CCH * CCH; idx += 128)
            Mws[b * 256 + idx] = ga * W_exp[ea * 256 + idx] + gb * W_exp[eb * 256 + idx];
        if (t < CCH)
            biasws[b * CCH + t] = ga * b_exp[ea * CCH + t] + gb * b_exp[eb * CCH + t];
    }
}

// ---------------- Kernel 2: out = x + x @ M_b + bias_b (memory-bound) ----------------
__global__ __launch_bounds__(256) void k2_out(
    const float* __restrict__ x,
    const float* __restrict__ Mws,
    const float* __restrict__ biasws,
    float* __restrict__ out)
{
    const int blk = blockIdx.x;
    const int b = blk >> 3;            // SPLIT = 8
    const int chunk = blk & 7;
    const int t = threadIdx.x;
    const int lane = t & 63;
    const int wv = t >> 6;
    const int cg = lane & 3;
    const int prow = (wv << 4) + (lane >> 2);

    const float* Mb = Mws + b * 256 + cg * 4;
    float4 m0  = *(const float4*)(Mb + 0 * 16);
    float4 m1  = *(const float4*)(Mb + 1 * 16);
    float4 m2  = *(const float4*)(Mb + 2 * 16);
    float4 m3  = *(const float4*)(Mb + 3 * 16);
    float4 m4  = *(const float4*)(Mb + 4 * 16);
    float4 m5  = *(const float4*)(Mb + 5 * 16);
    float4 m6  = *(const float4*)(Mb + 6 * 16);
    float4 m7  = *(const float4*)(Mb + 7 * 16);
    float4 m8  = *(const float4*)(Mb + 8 * 16);
    float4 m9  = *(const float4*)(Mb + 9 * 16);
    float4 m10 = *(const float4*)(Mb + 10 * 16);
    float4 m11 = *(const float4*)(Mb + 11 * 16);
    float4 m12 = *(const float4*)(Mb + 12 * 16);
    float4 m13 = *(const float4*)(Mb + 13 * 16);
    float4 m14 = *(const float4*)(Mb + 14 * 16);
    float4 m15 = *(const float4*)(Mb + 15 * 16);
    float4 bias = *(const float4*)(biasws + b * CCH + cg * 4);

    const size_t base = (size_t)b * (LENL * NCH * CCH);
    const float* xb = x + base;
    float* ob = out + base;
    const int posBase = chunk * (LENL * NCH / SPLIT);

    #pragma unroll
    for (int i = 0; i < (LENL * NCH / SPLIT) / 64; ++i) {
        int pos = posBase + i * 64 + prow;
        const float* xr = xb + (size_t)pos * CCH;
        float4 x0 = *(const float4*)(xr + 0);
        float4 x1 = *(const float4*)(xr + 4);
        float4 x2 = *(const float4*)(xr + 8);
        float4 x3 = *(const float4*)(xr + 12);
        float4 acc = bias;
        #define STEPF(v, M) acc.x += (v) * (M).x; acc.y += (v) * (M).y; acc.z += (v) * (M).z; acc.w += (v) * (M).w;
        STEPF(x0.x, m0)  STEPF(x0.y, m1)  STEPF(x0.z, m2)  STEPF(x0.w, m3)
        STEPF(x1.x, m4)  STEPF(x1.y, m5)  STEPF(x1.z, m6)  STEPF(x1.w, m7)
        STEPF(x2.x, m8)  STEPF(x2.y, m9)  STEPF(x2.z, m10) STEPF(x2.w, m11)
        STEPF(x3.x, m12) STEPF(x3.y, m13) STEPF(x3.z, m14) STEPF(x3.w, m15)
        #undef STEPF
        float4 xo = (cg == 0) ? x0 : ((cg == 1) ? x1 : ((cg == 2) ? x2 : x3));
        acc.x += xo.x; acc.y += xo.y; acc.z += xo.z; acc.w += xo.w;
        *(float4*)(ob + (size_t)pos * CCH + cg * 4) = acc;
    }
}

// ---------------- Kernel 3: balance loss ----------------
__global__ __launch_bounds__(256) void k3_loss(
    const float* __restrict__ gws, float* __restrict__ loss_out)
{
    __shared__ float sh[8][256];
    const int t = threadIdx.x;
    float imp[4] = {0, 0, 0, 0}, ld[4] = {0, 0, 0, 0};
    for (int b = t; b < NB; b += 256) {
        #pragma unroll
        for (int e = 0; e < 4; ++e) {
            float v = gws[b * 4 + e];
            imp[e] += v;
            ld[e] += (v > 0.f) ? 1.f : 0.f;
        }
    }
    #pragma unroll
    for (int e = 0; e < 4; ++e) { sh[e][t] = imp[e]; sh[4 + e][t] = ld[e]; }
    __syncthreads();
    if (t < 8) {
        float s = 0.f;
        for (int i = 0; i < 256; ++i) s += sh[t][i];
        sh[t][0] = s;
    }
    __syncthreads();
    if (t == 0) {
        float a = sh[0][0], b2 = sh[1][0], c = sh[2][0], d = sh[3][0];
        float mean = (a + b2 + c + d) * 0.25f;
        float var = ((a - mean) * (a - mean) + (b2 - mean) * (b2 - mean) +
                     (c - mean) * (c - mean) + (d - mean) * (d - mean)) * (1.f / 3.f);
        float L1 = var / (mean * mean + 1e-10f);
        a = sh[4][0]; b2 = sh[5][0]; c = sh[6][0]; d = sh[7][0];
        mean = (a + b2 + c + d) * 0.25f;
        var = ((a - mean) * (a - mean) + (b2 - mean) * (b2 - mean) +
               (c - mean) * (c - mean) + (d - mean) * (d - mean)) * (1.f / 3.f);
        float L2 = var / (mean * mean + 1e-10f);
        *loss_out = 0.01f * (L1 + L2);
    }
}

extern "C" void kernel_launch(void* const* d_in, const int* in_sizes, int n_in,
                              void* d_out, int out_size, void* d_ws, size_t ws_size,
                              hipStream_t stream)
{
    const float* x       = (const float*)d_in[0];
    const float* W_start = (const float*)d_in[1];
    const float* b_start = (const float*)d_in[2];
    const float* W_gate  = (const float*)d_in[3];
    const float* b_gate  = (const float*)d_in[4];
    const float* W_exp   = (const float*)d_in[5];
    const float* b_exp   = (const float*)d_in[6];
    float* out = (float*)d_out;

    float* ws = (float*)d_ws;
    float* xs_t    = ws;                               // 512*32*96 = 1,572,864
    float2* selAB  = (float2*)(ws + 1572864);          // 49,152 float2 (98,304 floats)
    int* selFq     = (int*)(ws + 1572864 + 98304);     // 49,152 ints
    float* Mws     = ws + 1572864 + 98304 + 49152;     // 131,072
    float* biasws  = Mws + NB * 256;                   // 8,192
    float* gws     = biasws + NB * CCH;                // 2,048

    k_dft<<<NB * 2, 256, 0, stream>>>(x, W_start, xs_t, selAB, selFq);
    k_gate<<<NB, 128, 0, stream>>>(xs_t, selAB, selFq, W_start, b_start,
                                   W_gate, b_gate, W_exp, b_exp, Mws, biasws, gws);
    k2_out<<<NB * SPLIT, 256, 0, stream>>>(x, Mws, biasws, out);
    k3_loss<<<1, 256, 0, stream>>>(gws, out + (size_t)out_size - 1);
}

// Round 3
// 74.436 us; speedup vs baseline: 1.5525x; 1.1461x over previous
//
#include <hip/hip_runtime.h>
#include <math.h>

#define LENL 96
#define NCH 32
#define CCH 16
#define NEXP 4
#define NB 512
#define SPLIT 8
#define TWO_PI_D 6.283185307179586476925286766559
#define PADX 98   // xd row stride (even -> 16B-aligned double2 rows; 4n+2l banks)
#define PADM 49   // mags/reF/imF row stride

// ---------------- Fused gating kernel: one block per batch row ----------------
// Phase 1: gather x[b,:,:,0] -> LDS fp64. Phase 2: Goertzel DFT (wave w = series
// 4w..4w+3, lane = freq-1). Phase 3: top-3 per series. Phase 4: y/trend/seasonal
// -> g. Phase 5: logits/top-2/softmax -> combined expert matrix M_b + bias.
__global__ __launch_bounds__(512) void k_fused(
    const float* __restrict__ x,        // (512,96,32,16)
    const float* __restrict__ W_start,  // (1,32)
    const float* __restrict__ b_start,  // (1,)
    const float* __restrict__ W_gate,   // (4,96)
    const float* __restrict__ b_gate,   // (4,)
    const float* __restrict__ W_exp,    // (4,16,16)
    const float* __restrict__ b_exp,    // (4,16)
    float* __restrict__ Mws,            // (512,256)
    float* __restrict__ biasws,         // (512,16)
    float* __restrict__ gws)            // (512,4)
{
    const int b = blockIdx.x, t = threadIdx.x;
    const int w = t >> 6, lane = t & 63;

    __shared__ __align__(16) double xd[NCH][PADX];
    __shared__ double mags[NCH][PADM];
    __shared__ float reF[NCH][PADM], imF[NCH][PADM];
    __shared__ float2 twf[LENL];
    __shared__ float Wsm[NCH];
    __shared__ float As[96], Bs[96];
    __shared__ int Fs[96];
    __shared__ float g_sh[LENL];
    __shared__ float logit_s[NEXP];
    __shared__ float gsel[2];
    __shared__ int esel[2];

    if (t < LENL) {
        double ang = TWO_PI_D * (double)t / 96.0;
        twf[t] = make_float2((float)cos(ang), (float)(-sin(ang)));
    }
    if (t < NCH) Wsm[t] = W_start[t];
    for (int idx = t; idx < NCH * LENL; idx += 512) {
        int l = idx >> 5, n = idx & 31;
        xd[n][l] = (double)x[(((size_t)b * LENL + l) * NCH + n) * CCH];
    }
    __syncthreads();

    // ---- Goertzel: s[l] = x[l] + 2cos(w)s[l-1] - s[l-2]; X = e^{iw}(s1 - e^{-iw}s2)
    if (lane < 47) {
        const double w0 = TWO_PI_D * (double)(lane + 1) / 96.0;
        const double c2 = 2.0 * cos(w0);
        double s1a = 0, s2a = 0, s1b = 0, s2b = 0;
        double s1c = 0, s2c = 0, s1d = 0, s2d = 0;
        const double2* pa = (const double2*)&xd[w * 4 + 0][0];
        const double2* pb = (const double2*)&xd[w * 4 + 1][0];
        const double2* pc = (const double2*)&xd[w * 4 + 2][0];
        const double2* pd = (const double2*)&xd[w * 4 + 3][0];
        #pragma unroll 2
        for (int j = 0; j < 48; ++j) {
            double2 va = pa[j], vb = pb[j], vc = pc[j], vd = pd[j];
            double tt;
            tt = fma(c2, s1a, va.x - s2a); s2a = s1a; s1a = tt;
            tt = fma(c2, s1b, vb.x - s2b); s2b = s1b; s1b = tt;
            tt = fma(c2, s1c, vc.x - s2c); s2c = s1c; s1c = tt;
            tt = fma(c2, s1d, vd.x - s2d); s2d = s1d; s1d = tt;
            tt = fma(c2, s1a, va.y - s2a); s2a = s1a; s1a = tt;
            tt = fma(c2, s1b, vb.y - s2b); s2b = s1b; s1b = tt;
            tt = fma(c2, s1c, vc.y - s2c); s2c = s1c; s1c = tt;
            tt = fma(c2, s1d, vd.y - s2d); s2d = s1d; s1d = tt;
        }
        const double cw = cos(w0), sw = sin(w0);
        #define GFIN(S1, S2, ROW) { \
            double yr = (S1) - cw * (S2); \
            double yi = sw * (S2); \
            double Xr = cw * yr - sw * yi; \
            double Xi = cw * yi + sw * yr; \
            mags[ROW][lane] = Xr * Xr + Xi * Xi; \
            reF[ROW][lane] = (float)Xr; imF[ROW][lane] = (float)Xi; }
        GFIN(s1a, s2a, w * 4 + 0)
        GFIN(s1b, s2b, w * 4 + 1)
        GFIN(s1c, s2c, w * 4 + 2)
        GFIN(s1d, s2d, w * 4 + 3)
        #undef GFIN
    }
    __syncthreads();

    // ---- top-3 |X|^2 per series (strict > keeps lowest index on ties)
    if (t < NCH) {
        double m1 = -1.0, m2 = -1.0, m3 = -1.0;
        int i1 = 0, i2 = 0, i3 = 0;
        for (int fi = 0; fi < 47; ++fi) {
            double mg = mags[t][fi];
            if (mg > m1)      { m3 = m2; i3 = i2; m2 = m1; i2 = i1; m1 = mg; i1 = fi; }
            else if (mg > m2) { m3 = m2; i3 = i2; m2 = mg; i2 = fi; }
            else if (mg > m3) { m3 = mg; i3 = fi; }
        }
        const float sc = Wsm[t] * (2.0f / 96.0f);
        Fs[t * 3 + 0] = i1 + 1; As[t * 3 + 0] = sc * reF[t][i1]; Bs[t * 3 + 0] = sc * imF[t][i1];
        Fs[t * 3 + 1] = i2 + 1; As[t * 3 + 1] = sc * reF[t][i2]; Bs[t * 3 + 1] = sc * imF[t][i2];
        Fs[t * 3 + 2] = i3 + 1; As[t * 3 + 2] = sc * reF[t][i3]; Bs[t * 3 + 2] = sc * imF[t][i3];
    }
    __syncthreads();

    // ---- y = x.Ws ; g = y + trend(y) + seasonal + b_start   (trend is linear)
    if (t < LENL) {
        float yv = 0.f;
        #pragma unroll
        for (int n = 0; n < NCH; ++n) yv += (float)xd[n][t] * Wsm[n];
        g_sh[t] = yv;   // stash y; need whole y for trend windows
    }
    __syncthreads();
    float gval = 0.f;
    if (t < LENL) {
        float s4 = 0.f;
        #pragma unroll
        for (int j = -1; j <= 2; ++j) {
            int li = t + j; li = li < 0 ? 0 : (li > 95 ? 95 : li);
            s4 += g_sh[li];
        }
        float s8 = s4;
        {
            int li;
            li = t - 3; li = li < 0 ? 0 : li; s8 += g_sh[li];
            li = t - 2; li = li < 0 ? 0 : li; s8 += g_sh[li];
            li = t + 3; li = li > 95 ? 95 : li; s8 += g_sh[li];
            li = t + 4; li = li > 95 ? 95 : li; s8 += g_sh[li];
        }
        float s12 = s8;
        {
            int li;
            li = t - 5; li = li < 0 ? 0 : li; s12 += g_sh[li];
            li = t - 4; li = li < 0 ? 0 : li; s12 += g_sh[li];
            li = t + 5; li = li > 95 ? 95 : li; s12 += g_sh[li];
            li = t + 6; li = li > 95 ? 95 : li; s12 += g_sh[li];
        }
        float tr = (s4 * 0.25f + s8 * 0.125f + s12 * (1.f / 12.f)) * (1.f / 3.f);
        float se = 0.f;
        for (int k = 0; k < 96; ++k) {
            int m = (Fs[k] * t) % LENL;
            float2 c = twf[m];
            se += As[k] * c.x + Bs[k] * c.y;
        }
        gval = g_sh[t] + tr + se + b_start[0];
    }
    __syncthreads();
    if (t < LENL) g_sh[t] = gval;
    __syncthreads();

    if (t < NEXP) {
        float acc = b_gate[t];
        for (int l = 0; l < LENL; ++l) acc += g_sh[l] * W_gate[t * LENL + l];
        logit_s[t] = acc;
    }
    __syncthreads();

    if (t == 0) {
        int i1 = 0;
        for (int e = 1; e < NEXP; ++e) if (logit_s[e] > logit_s[i1]) i1 = e;
        int i2 = (i1 == 0) ? 1 : 0;
        for (int e = 0; e < NEXP; ++e) if (e != i1 && logit_s[e] > logit_s[i2]) i2 = e;
        float v1 = logit_s[i1], v2 = logit_s[i2];
        float e2v = expf(v2 - v1);
        float inv = 1.f / (1.f + e2v);
        esel[0] = i1; esel[1] = i2; gsel[0] = inv; gsel[1] = e2v * inv;
        for (int e = 0; e < NEXP; ++e)
            gws[b * NEXP + e] = (e == i1) ? inv : ((e == i2) ? e2v * inv : 0.f);
    }
    __syncthreads();

    {
        float ga = gsel[0], gb = gsel[1];
        int ea = esel[0], eb = esel[1];
        if (t < CCH * CCH)
            Mws[b * 256 + t] = ga * W_exp[ea * 256 + t] + gb * W_exp[eb * 256 + t];
        if (t >= 256 && t < 256 + CCH) {
            int c = t - 256;
            biasws[b * CCH + c] = ga * b_exp[ea * CCH + c] + gb * b_exp[eb * CCH + c];
        }
    }
}

// ---------------- Kernel 2: out = x + x @ M_b + bias_b (memory-bound) ----------------
__global__ __launch_bounds__(256) void k2_out(
    const float* __restrict__ x,
    const float* __restrict__ Mws,
    const float* __restrict__ biasws,
    float* __restrict__ out)
{
    const int blk = blockIdx.x;
    const int b = blk >> 3;            // SPLIT = 8
    const int chunk = blk & 7;
    const int t = threadIdx.x;
    const int lane = t & 63;
    const int wv = t >> 6;
    const int cg = lane & 3;
    const int prow = (wv << 4) + (lane >> 2);

    const float* Mb = Mws + b * 256 + cg * 4;
    float4 m0  = *(const float4*)(Mb + 0 * 16);
    float4 m1  = *(const float4*)(Mb + 1 * 16);
    float4 m2  = *(const float4*)(Mb + 2 * 16);
    float4 m3  = *(const float4*)(Mb + 3 * 16);
    float4 m4  = *(const float4*)(Mb + 4 * 16);
    float4 m5  = *(const float4*)(Mb + 5 * 16);
    float4 m6  = *(const float4*)(Mb + 6 * 16);
    float4 m7  = *(const float4*)(Mb + 7 * 16);
    float4 m8  = *(const float4*)(Mb + 8 * 16);
    float4 m9  = *(const float4*)(Mb + 9 * 16);
    float4 m10 = *(const float4*)(Mb + 10 * 16);
    float4 m11 = *(const float4*)(Mb + 11 * 16);
    float4 m12 = *(const float4*)(Mb + 12 * 16);
    float4 m13 = *(const float4*)(Mb + 13 * 16);
    float4 m14 = *(const float4*)(Mb + 14 * 16);
    float4 m15 = *(const float4*)(Mb + 15 * 16);
    float4 bias = *(const float4*)(biasws + b * CCH + cg * 4);

    const size_t base = (size_t)b * (LENL * NCH * CCH);
    const float* xb = x + base;
    float* ob = out + base;
    const int posBase = chunk * (LENL * NCH / SPLIT);

    #pragma unroll
    for (int i = 0; i < (LENL * NCH / SPLIT) / 64; ++i) {
        int pos = posBase + i * 64 + prow;
        const float* xr = xb + (size_t)pos * CCH;
        float4 x0 = *(const float4*)(xr + 0);
        float4 x1 = *(const float4*)(xr + 4);
        float4 x2 = *(const float4*)(xr + 8);
        float4 x3 = *(const float4*)(xr + 12);
        float4 acc = bias;
        #define STEPF(v, M) acc.x += (v) * (M).x; acc.y += (v) * (M).y; acc.z += (v) * (M).z; acc.w += (v) * (M).w;
        STEPF(x0.x, m0)  STEPF(x0.y, m1)  STEPF(x0.z, m2)  STEPF(x0.w, m3)
        STEPF(x1.x, m4)  STEPF(x1.y, m5)  STEPF(x1.z, m6)  STEPF(x1.w, m7)
        STEPF(x2.x, m8)  STEPF(x2.y, m9)  STEPF(x2.z, m10) STEPF(x2.w, m11)
        STEPF(x3.x, m12) STEPF(x3.y, m13) STEPF(x3.z, m14) STEPF(x3.w, m15)
        #undef STEPF
        float4 xo = (cg == 0) ? x0 : ((cg == 1) ? x1 : ((cg == 2) ? x2 : x3));
        acc.x += xo.x; acc.y += xo.y; acc.z += xo.z; acc.w += xo.w;
        *(float4*)(ob + (size_t)pos * CCH + cg * 4) = acc;
    }
}

// ---------------- Kernel 3: balance loss ----------------
__global__ __launch_bounds__(256) void k3_loss(
    const float* __restrict__ gws, float* __restrict__ loss_out)
{
    __shared__ float sh[8][256];
    const int t = threadIdx.x;
    float imp[4] = {0, 0, 0, 0}, ld[4] = {0, 0, 0, 0};
    for (int b = t; b < NB; b += 256) {
        #pragma unroll
        for (int e = 0; e < 4; ++e) {
            float v = gws[b * 4 + e];
            imp[e] += v;
            ld[e] += (v > 0.f) ? 1.f : 0.f;
        }
    }
    #pragma unroll
    for (int e = 0; e < 4; ++e) { sh[e][t] = imp[e]; sh[4 + e][t] = ld[e]; }
    __syncthreads();
    if (t < 8) {
        float s = 0.f;
        for (int i = 0; i < 256; ++i) s += sh[t][i];
        sh[t][0] = s;
    }
    __syncthreads();
    if (t == 0) {
        float a = sh[0][0], b2 = sh[1][0], c = sh[2][0], d = sh[3][0];
        float mean = (a + b2 + c + d) * 0.25f;
        float var = ((a - mean) * (a - mean) + (b2 - mean) * (b2 - mean) +
                     (c - mean) * (c - mean) + (d - mean) * (d - mean)) * (1.f / 3.f);
        float L1 = var / (mean * mean + 1e-10f);
        a = sh[4][0]; b2 = sh[5][0]; c = sh[6][0]; d = sh[7][0];
        mean = (a + b2 + c + d) * 0.25f;
        var = ((a - mean) * (a - mean) + (b2 - mean) * (b2 - mean) +
               (c - mean) * (c - mean) + (d - mean) * (d - mean)) * (1.f / 3.f);
        float L2 = var / (mean * mean + 1e-10f);
        *loss_out = 0.01f * (L1 + L2);
    }
}

extern "C" void kernel_launch(void* const* d_in, const int* in_sizes, int n_in,
                              void* d_out, int out_size, void* d_ws, size_t ws_size,
                              hipStream_t stream)
{
    const float* x       = (const float*)d_in[0];
    const float* W_start = (const float*)d_in[1];
    const float* b_start = (const float*)d_in[2];
    const float* W_gate  = (const float*)d_in[3];
    const float* b_gate  = (const float*)d_in[4];
    const float* W_exp   = (const float*)d_in[5];
    const float* b_exp   = (const float*)d_in[6];
    float* out = (float*)d_out;

    float* ws = (float*)d_ws;
    float* Mws    = ws;                      // 512*256
    float* biasws = Mws + NB * 256;          // 512*16
    float* gws    = biasws + NB * CCH;       // 512*4

    k_fused<<<NB, 512, 0, stream>>>(x, W_start, b_start, W_gate, b_gate,
                                    W_exp, b_exp, Mws, biasws, gws);
    k2_out<<<NB * SPLIT, 256, 0, stream>>>(x, Mws, biasws, out);
    k3_loss<<<1, 256, 0, stream>>>(gws, out + (size_t)out_size - 1);
}